// Round 4
// baseline (269.933 us; speedup 1.0000x reference)
//
#include <hip/hip_runtime.h>

#define NB 128
#define CC 1024
#define HWP 196
#define HH 14
#define OO 256

typedef unsigned short ushort_t;
typedef __attribute__((ext_vector_type(4))) short short4v;
typedef __attribute__((ext_vector_type(8))) short short8;
typedef __attribute__((ext_vector_type(4))) float float4v;

__device__ __forceinline__ ushort_t f2bf(float v) {
  union { float f; unsigned int u; } c; c.f = v;
  unsigned int u = c.u;
  unsigned int r = (u + 0x7FFFu + ((u >> 16) & 1u)) >> 16;   // RNE
  return (ushort_t)r;
}

// K1: fused (a) partial channel-sum + same-layout bf16 copy of x, (b) weight
// bf16 cast.
// Reduce: one wave per (n,cg); lanes 0..48 hold float4 (4 consecutive p).
// Component-wise accumulation over c=0..127 ascending — bit-identical per-p
// FP order (medK rank selection is knife-edge sensitive to this order;
// do NOT reorder the c loop). The xb16 store is independent of the add chain.
__global__ __launch_bounds__(256) void k_prep(const float* __restrict__ x,
                                              const float* __restrict__ wmax,
                                              const float* __restrict__ wmed,
                                              float* __restrict__ partial,
                                              ushort_t* __restrict__ wb,
                                              ushort_t* __restrict__ xb16) {
  const int b = blockIdx.x, t = threadIdx.x;
  if (b >= 256) {   // weight cast: 2048 blocks x 256 = 2*OO*CC elements
    int idx = (b - 256) * 256 + t;
    int z = idx >> 18;
    int r = idx & (OO * CC - 1);
    const float* w = z ? wmed : wmax;
    wb[idx] = f2bf(w[r]);
    return;
  }
  const int unit = b * 4 + (t >> 6);     // (n,cg) unit, one per wave
  const int lane = t & 63;
  if (lane >= 49) return;                // 49 float4s cover 196 floats
  const int n = unit >> 3, cg = unit & 7;
  const float4 * base = (const float4*)(x + ((size_t)n * CC + (size_t)cg * 128) * HWP);
  ushort_t* xo = xb16 + ((size_t)n * CC + (size_t)cg * 128) * HWP + lane * 4;
  float4 s = {0.f, 0.f, 0.f, 0.f};
  #pragma unroll 16
  for (int c = 0; c < 128; ++c) {
    float4 v = base[c * 49 + lane];
    s.x += v.x; s.y += v.y; s.z += v.z; s.w += v.w;   // per-p sequential order
    short4v o;
    o[0] = (short)f2bf(v.x); o[1] = (short)f2bf(v.y);
    o[2] = (short)f2bf(v.z); o[3] = (short)f2bf(v.w);
    *(short4v*)(xo + (size_t)c * HWP) = o;            // 392B/row, coalesced
  }
  ((float4*)(partial + ((size_t)n * 8 + cg) * HWP))[lane] = s;
}

// K1.5: extract pass. Block = (n, quarter of channels); 256 threads (4 waves).
// Recomputes the stable rank-select (bit-identical code), then gathers from
// the bf16 copy xb16 with R0's proven merge-friendly mapping: lane = (j fast,
// g slow) so each load instr covers 2 rows x 32 positions (~12 distinct 64B
// lines from 64 lanes; rows are 392B so the whole gather is ~50MB of line
// traffic, chip-wide, z-deduplicated). 32-deep ILP per thread, no f2bf.
// Staged in LDS then flushed fully coalesced (short8) to af[n][j][c].
__global__ __launch_bounds__(256) void k_extract(const ushort_t* __restrict__ xb16,
                                                 const float* __restrict__ partial,
                                                 ushort_t* __restrict__ af) {
  __shared__ float fre[HWP];
  __shared__ int sc[32];
  __shared__ ushort_t ob[32][264];   // 16.9 KB, row stride 528B (16B-aligned)

  const int b = blockIdx.x;
  const int n = b >> 2, q = b & 3;
  const int t = threadIdx.x;

  // ---- rank select: EXACT same ops/order as k_main (must stay identical) ----
  if (t < HWP) {
    float s = 0.f;
    #pragma unroll
    for (int g = 0; g < 8; ++g) s += partial[((size_t)n * 8 + g) * HWP + t];
    fre[t] = s;
  }
  __syncthreads();
  if (t < HWP) {
    float v = fre[t];
    int rank = 0;
    #pragma unroll 4
    for (int q2 = 0; q2 < HWP; ++q2) {
      float u = fre[q2];
      rank += ((u > v) || (u == v && q2 < t)) ? 1 : 0;
    }
    if (rank < 16) sc[rank] = t;                           // maxK: ranks 0..15
    else if (rank >= 89 && rank < 105) sc[rank - 73] = t;  // medK: ranks 89..104
  }
  __syncthreads();

  // ---- gather: thread (j = t&31, g = t>>5): 32 loads down channels ----
  {
    const int j = t & 31, g = t >> 5;          // g in 0..7
    const int sp = sc[j];
    const ushort_t* src = xb16 + ((size_t)n * CC + q * 256 + g * 32) * HWP + sp;
    ushort_t v[32];
    #pragma unroll
    for (int u = 0; u < 32; ++u) v[u] = src[(size_t)u * HWP];
    #pragma unroll
    for (int u = 0; u < 32; ++u) ob[j][g * 32 + u] = v[u];
  }
  __syncthreads();

  // ---- flush: coalesced short8; per instr 2 j-rows x 512B segments ----
  #pragma unroll
  for (int it = 0; it < 4; ++it) {
    int f = it * 2048 + t * 8;
    int jj = f >> 8, cc = f & 255;
    *(short8*)(af + ((size_t)n * 32 + jj) * CC + q * 256 + cc) =
        *(const short8*)&ob[jj][cc];
  }
}

// K2: per (n,z) block, 512 threads (8 waves): in-block exact stable rank-select;
// A-load is a fully coalesced 32 KB bf16 copy from A_f (scatter hoisted to
// k_extract); bf16 MFMA GEMM (8 waves x 32 cols); BN+ReLU; Lnorm apply;
// writes graphs (+ rows/cols from z==0 blocks).
__global__ __launch_bounds__(512, 2) void k_main(
    const float* __restrict__ partial,
    const ushort_t* __restrict__ wb,
    const ushort_t* __restrict__ af,
    const float* __restrict__ g_max, const float* __restrict__ b_max,
    const float* __restrict__ m_max, const float* __restrict__ v_max,
    const float* __restrict__ g_med, const float* __restrict__ b_med,
    const float* __restrict__ m_med, const float* __restrict__ v_med,
    float* __restrict__ out) {
  constexpr int AP = 1032;               // padded row stride (ushorts)
  __shared__ alignas(16) ushort_t A_sh[16 * AP];   // 33 KB
  __shared__ float fre[HWP];
  __shared__ int sc[32];
  __shared__ float Lsh[16][17];
  __shared__ float dinv[16];
  __shared__ float y_sh[16][257];        // 16.4 KB

  const int n = blockIdx.x;
  const int z = blockIdx.y;
  const int t = threadIdx.x;

  // ---- select: fre = sum of 8 partials (sequential); stable ranks ----
  if (t < HWP) {
    float s = 0.f;
    #pragma unroll
    for (int g = 0; g < 8; ++g) s += partial[((size_t)n * 8 + g) * HWP + t];
    fre[t] = s;
  }
  __syncthreads();
  if (t < HWP) {
    float v = fre[t];
    int rank = 0;
    #pragma unroll 4
    for (int q = 0; q < HWP; ++q) {
      float u = fre[q];
      rank += ((u > v) || (u == v && q < t)) ? 1 : 0;
    }
    if (rank < 16) sc[rank] = t;                           // maxK: ranks 0..15
    else if (rank >= 89 && rank < 105) sc[rank - 73] = t;  // medK: ranks 89..104
  }
  __syncthreads();

  if (z == 0 && t < 32) {
    int p = sc[t];
    out[2 * NB * 4096 + n * 32 + t] = (float)(p / HH);            // rows
    out[2 * NB * 4096 + NB * 32 + n * 32 + t] = (float)(p % HH);  // cols
  }

  // ---- A load: 16 rows x 2 KB from A_f, fully coalesced ----
  {
    const int j = t >> 5;              // row 0..15
    const int u = t & 31;              // 32 threads per row
    const ushort_t* src = af + ((size_t)n * 32 + z * 16 + j) * CC + u * 8;
    ushort_t* dst = &A_sh[j * AP + u * 8];
    #pragma unroll
    for (int q = 0; q < 4; ++q)
      *(short8*)(dst + q * 256) = *(const short8*)(src + q * 256);
  }
  // ---- L matrix ----
  if (t < 256) {
    const int i = t >> 4, j = t & 15;
    int pi = sc[z * 16 + i], pj = sc[z * 16 + j];
    float dr = (float)(pi / HH - pj / HH);
    float dc = (float)(pi % HH - pj % HH);
    Lsh[i][j] = 1.0f / (1.0f + sqrtf(dr * dr + dc * dc));
  }
  __syncthreads();
  if (t < 16) {
    float s = 0.f;
    #pragma unroll
    for (int j = 0; j < 16; ++j) s += Lsh[t][j];
    dinv[t] = rsqrtf(s);
  }

  const int w = t >> 6;                  // 8 waves, 32 output cols each
  const int l = t & 63;
  const int m = l & 15;
  const int quad = l >> 4;

  const ushort_t* Arow = &A_sh[m * AP + quad * 8];
  const ushort_t* B0 = wb + (size_t)z * (OO * CC) + (size_t)(w * 32 + m) * CC + quad * 8;

  float4v acc0 = {0.f, 0.f, 0.f, 0.f};
  float4v acc1 = acc0;

  __syncthreads();   // dinv + A_sh visible

  #pragma unroll 4
  for (int k0 = 0; k0 < CC; k0 += 32) {
    short8 a  = *reinterpret_cast<const short8*>(Arow + k0);
    short8 b0 = *reinterpret_cast<const short8*>(B0 + k0);
    short8 b1 = *reinterpret_cast<const short8*>(B0 + 16 * CC + k0);
    acc0 = __builtin_amdgcn_mfma_f32_16x16x32_bf16(a, b0, acc0, 0, 0, 0);
    acc1 = __builtin_amdgcn_mfma_f32_16x16x32_bf16(a, b1, acc1, 0, 0, 0);
  }

  const float* gp = z ? g_med : g_max;
  const float* bp = z ? b_med : b_max;
  const float* mp = z ? m_med : m_max;
  const float* vp = z ? v_med : v_max;

  // BN + ReLU; scatter C-layout (col=lane&15, row=quad*4+reg) to LDS
  #pragma unroll
  for (int tt = 0; tt < 2; ++tt) {
    float4v av = tt ? acc1 : acc0;
    int o = w * 32 + tt * 16 + m;
    float scale = gp[o] * rsqrtf(vp[o] + 1e-5f);
    float shift = bp[o] - mp[o] * scale;
    #pragma unroll
    for (int r = 0; r < 4; ++r) {
      int j = quad * 4 + r;
      float y = av[r] * scale + shift;
      y = fmaxf(y, 0.f);
      y_sh[j][o] = y * dinv[j];
    }
  }
  __syncthreads();

  // out[n,z,i,o] = dinv_i * sum_j L[i][j] * (dinv_j * y[j][o])
  // 512 threads: o = t&255, half-i-range per t>>8
  {
    const int o = t & 255;
    const int ih = (t >> 8) * 8;
    float yp[16];
    #pragma unroll
    for (int j = 0; j < 16; ++j) yp[j] = y_sh[j][o];
    float* ob2 = out + (size_t)z * (NB * 4096) + (size_t)n * 4096 + o;
    #pragma unroll
    for (int i2 = 0; i2 < 8; ++i2) {
      const int i = ih + i2;
      float s = 0.f;
      #pragma unroll
      for (int j = 0; j < 16; ++j) s = fmaf(Lsh[i][j], yp[j], s);
      ob2[(size_t)i * OO] = s * dinv[i];
    }
  }
}

extern "C" void kernel_launch(void* const* d_in, const int* in_sizes, int n_in,
                              void* d_out, int out_size, void* d_ws, size_t ws_size,
                              hipStream_t stream) {
  const float* x     = (const float*)d_in[0];
  const float* w_max = (const float*)d_in[2];
  const float* g_max = (const float*)d_in[3];
  const float* b_max = (const float*)d_in[4];
  const float* m_max = (const float*)d_in[5];
  const float* v_max = (const float*)d_in[6];
  const float* w_med = (const float*)d_in[7];
  const float* g_med = (const float*)d_in[8];
  const float* b_med = (const float*)d_in[9];
  const float* m_med = (const float*)d_in[10];
  const float* v_med = (const float*)d_in[11];
  float* out = (float*)d_out;

  float* ws_f = (float*)d_ws;
  float* partial  = ws_f;                        // 128*8*196 floats   (0.80 MB)
  ushort_t* wb    = (ushort_t*)(ws_f + 200704);  // 2*256*1024 ushorts (1 MB)
  ushort_t* af    = wb + 2 * OO * CC;            // 128*32*1024 bf16   (8 MB)
  ushort_t* xb16  = af + (size_t)NB * 32 * CC;   // 128*1024*196 bf16  (51.4 MB)

  k_prep<<<dim3(256 + 2048), 256, 0, stream>>>(x, w_max, w_med, partial, wb, xb16);
  k_extract<<<dim3(NB * 4), 256, 0, stream>>>(xb16, partial, af);
  k_main<<<dim3(NB, 2), 512, 0, stream>>>(partial, wb, af,
                                          g_max, b_max, m_max, v_max,
                                          g_med, b_med, m_med, v_med, out);
}

// Round 5
// 221.926 us; speedup vs baseline: 1.2163x; 1.2163x over previous
//
#include <hip/hip_runtime.h>

#define NB 128
#define CC 1024
#define HWP 196
#define HH 14
#define OO 256

typedef unsigned short ushort_t;
typedef __attribute__((ext_vector_type(8))) short short8;
typedef __attribute__((ext_vector_type(4))) float float4v;

__device__ __forceinline__ ushort_t f2bf(float v) {
  union { float f; unsigned int u; } c; c.f = v;
  unsigned int u = c.u;
  unsigned int r = (u + 0x7FFFu + ((u >> 16) & 1u)) >> 16;   // RNE
  return (ushort_t)r;
}

// K1 (EXACT R0 version): fused (a) partial channel-sum, (b) weight bf16 cast.
// Reduce: one wave per (n,cg); lanes 0..48 hold float4 (4 consecutive p).
// Component-wise accumulation over c=0..127 ascending — bit-identical per-p
// FP order (medK rank selection is knife-edge sensitive to this order;
// do NOT reorder the c loop).
__global__ __launch_bounds__(256) void k_prep(const float* __restrict__ x,
                                              const float* __restrict__ wmax,
                                              const float* __restrict__ wmed,
                                              float* __restrict__ partial,
                                              ushort_t* __restrict__ wb) {
  const int b = blockIdx.x, t = threadIdx.x;
  if (b >= 256) {   // weight cast: 2048 blocks x 256 = 2*OO*CC elements
    int idx = (b - 256) * 256 + t;
    int z = idx >> 18;
    int r = idx & (OO * CC - 1);
    const float* w = z ? wmed : wmax;
    wb[idx] = f2bf(w[r]);
    return;
  }
  const int unit = b * 4 + (t >> 6);     // (n,cg) unit, one per wave
  const int lane = t & 63;
  if (lane >= 49) return;                // 49 float4s cover 196 floats
  const int n = unit >> 3, cg = unit & 7;
  const float4* base = (const float4*)(x + ((size_t)n * CC + (size_t)cg * 128) * HWP);
  float4 s = {0.f, 0.f, 0.f, 0.f};
  #pragma unroll 16
  for (int c = 0; c < 128; ++c) {
    float4 v = base[c * 49 + lane];
    s.x += v.x; s.y += v.y; s.z += v.z; s.w += v.w;   // per-p sequential order
  }
  ((float4*)(partial + ((size_t)n * 8 + cg) * HWP))[lane] = s;
}

// K2: ONE block per n (z-merged), 1024 threads (16 waves).
// select once; gather all 32 positions once (R0's merge-friendly lane map:
// per wave-instr 2 rows x 32 positions; 32-deep ILP per thread; loads issued
// before Lsh/dinv to hide L3 latency); A[32][1024] bf16 in LDS; GEMM with 16
// waves (wave = (z, 32-col group), per-wave code identical to R0); BN+ReLU;
// Lnorm apply for both z; rows/cols.
__global__ __launch_bounds__(1024, 1) void k_main(
    const float* __restrict__ x, const float* __restrict__ partial,
    const ushort_t* __restrict__ wb,
    const float* __restrict__ g_max, const float* __restrict__ b_max,
    const float* __restrict__ m_max, const float* __restrict__ v_max,
    const float* __restrict__ g_med, const float* __restrict__ b_med,
    const float* __restrict__ m_med, const float* __restrict__ v_med,
    float* __restrict__ out) {
  constexpr int AP = 1032;               // padded row stride (ushorts)
  __shared__ alignas(16) ushort_t A_sh[32 * AP];   // 66 KB
  __shared__ float fre[HWP];
  __shared__ int sc[32];
  __shared__ float Lsh[32][17];
  __shared__ float dinv[32];
  __shared__ float y_sh[32][257];        // 32.9 KB

  const int n = blockIdx.x;
  const int t = threadIdx.x;

  // ---- select: fre = sum of 8 partials (sequential); stable ranks ----
  if (t < HWP) {
    float s = 0.f;
    #pragma unroll
    for (int g = 0; g < 8; ++g) s += partial[((size_t)n * 8 + g) * HWP + t];
    fre[t] = s;
  }
  __syncthreads();
  if (t < HWP) {
    float v = fre[t];
    int rank = 0;
    #pragma unroll 4
    for (int q = 0; q < HWP; ++q) {
      float u = fre[q];
      rank += ((u > v) || (u == v && q < t)) ? 1 : 0;
    }
    if (rank < 16) sc[rank] = t;                           // maxK: ranks 0..15
    else if (rank >= 89 && rank < 105) sc[rank - 73] = t;  // medK: ranks 89..104
  }
  __syncthreads();

  if (t < 32) {
    int p = sc[t];
    out[2 * NB * 4096 + n * 32 + t] = (float)(p / HH);            // rows
    out[2 * NB * 4096 + NB * 32 + n * 32 + t] = (float)(p % HH);  // cols
  }

  // ---- gather: thread (j = t&31, g = t>>5) loads 32 channels at sc[j] ----
  // Issued before Lsh/dinv so the 32-deep load batch overlaps that work.
  const int gj = t & 31, gg = t >> 5;          // gg in 0..31
  const int sp = sc[gj];
  const float* gsrc = x + ((size_t)n * CC + gg * 32) * HWP + sp;
  float gv[32];
  #pragma unroll
  for (int u = 0; u < 32; ++u) gv[u] = gsrc[(size_t)u * HWP];

  // ---- L matrix (both z) ----
  if (t < 512) {
    const int z2 = t >> 8, i = (t >> 4) & 15, j = t & 15;
    int pi = sc[z2 * 16 + i], pj = sc[z2 * 16 + j];
    float dr = (float)(pi / HH - pj / HH);
    float dc = (float)(pi % HH - pj % HH);
    Lsh[z2 * 16 + i][j] = 1.0f / (1.0f + sqrtf(dr * dr + dc * dc));
  }
  __syncthreads();
  if (t < 32) {
    float s = 0.f;
    #pragma unroll
    for (int j = 0; j < 16; ++j) s += Lsh[t][j];
    dinv[t] = rsqrtf(s);
  }

  // ---- convert + stage A ----
  {
    ushort_t* arow = &A_sh[gj * AP + gg * 32];
    #pragma unroll
    for (int u = 0; u < 32; ++u) arow[u] = f2bf(gv[u]);
  }
  __syncthreads();   // A_sh + dinv visible

  // ---- GEMM: wave w -> zz = w>>3, col-group wc = w&7 (32 cols) ----
  const int w = t >> 6;
  const int l = t & 63;
  const int m = l & 15;
  const int quad = l >> 4;
  const int zz = w >> 3, wc = w & 7;

  const ushort_t* Arow = &A_sh[(zz * 16 + m) * AP + quad * 8];
  const ushort_t* B0 = wb + (size_t)zz * (OO * CC) + (size_t)(wc * 32 + m) * CC + quad * 8;

  float4v acc0 = {0.f, 0.f, 0.f, 0.f};
  float4v acc1 = acc0;

  #pragma unroll 4
  for (int k0 = 0; k0 < CC; k0 += 32) {
    short8 a  = *reinterpret_cast<const short8*>(Arow + k0);
    short8 b0 = *reinterpret_cast<const short8*>(B0 + k0);
    short8 b1 = *reinterpret_cast<const short8*>(B0 + 16 * CC + k0);
    acc0 = __builtin_amdgcn_mfma_f32_16x16x32_bf16(a, b0, acc0, 0, 0, 0);
    acc1 = __builtin_amdgcn_mfma_f32_16x16x32_bf16(a, b1, acc1, 0, 0, 0);
  }

  const float* gp = zz ? g_med : g_max;
  const float* bp = zz ? b_med : b_max;
  const float* mp = zz ? m_med : m_max;
  const float* vp = zz ? v_med : v_max;

  // BN + ReLU; scatter C-layout (col=lane&15, row=quad*4+reg) to LDS
  #pragma unroll
  for (int tt = 0; tt < 2; ++tt) {
    float4v av = tt ? acc1 : acc0;
    int o = wc * 32 + tt * 16 + m;
    float scale = gp[o] * rsqrtf(vp[o] + 1e-5f);
    float shift = bp[o] - mp[o] * scale;
    #pragma unroll
    for (int r = 0; r < 4; ++r) {
      int jl = quad * 4 + r;
      float y = av[r] * scale + shift;
      y = fmaxf(y, 0.f);
      y_sh[zz * 16 + jl][o] = y * dinv[zz * 16 + jl];
    }
  }
  __syncthreads();

  // out[n,z,i,o] = dinv_i * sum_j L[z][i][j] * (dinv_j * y[z][j][o])
  // 1024 threads: o = t&255, i-range gi*8..gi*8+7 (gi = t>>8 in 0..3)
  {
    const int o = t & 255;
    const int gi = t >> 8;
    const int z2 = gi >> 1;
    float yp[16];
    #pragma unroll
    for (int j = 0; j < 16; ++j) yp[j] = y_sh[z2 * 16 + j][o];
    float* ob = out + (size_t)z2 * (NB * 4096) + (size_t)n * 4096 + o;
    #pragma unroll
    for (int i2 = 0; i2 < 8; ++i2) {
      const int i = (gi & 1) * 8 + i2;         // local row within z
      float s = 0.f;
      #pragma unroll
      for (int j = 0; j < 16; ++j) s = fmaf(Lsh[z2 * 16 + i][j], yp[j], s);
      ob[(size_t)i * OO] = s * dinv[z2 * 16 + i];
    }
  }
}

extern "C" void kernel_launch(void* const* d_in, const int* in_sizes, int n_in,
                              void* d_out, int out_size, void* d_ws, size_t ws_size,
                              hipStream_t stream) {
  const float* x     = (const float*)d_in[0];
  const float* w_max = (const float*)d_in[2];
  const float* g_max = (const float*)d_in[3];
  const float* b_max = (const float*)d_in[4];
  const float* m_max = (const float*)d_in[5];
  const float* v_max = (const float*)d_in[6];
  const float* w_med = (const float*)d_in[7];
  const float* g_med = (const float*)d_in[8];
  const float* b_med = (const float*)d_in[9];
  const float* m_med = (const float*)d_in[10];
  const float* v_med = (const float*)d_in[11];
  float* out = (float*)d_out;

  float* ws_f = (float*)d_ws;
  float* partial  = ws_f;                        // 128*8*196 floats   (0.80 MB)
  ushort_t* wb    = (ushort_t*)(ws_f + 200704);  // 2*256*1024 ushorts (1 MB)

  k_prep<<<dim3(256 + 2048), 256, 0, stream>>>(x, w_max, w_med, partial, wb);
  k_main<<<dim3(NB), 1024, 0, stream>>>(x, partial, wb,
                                        g_max, b_max, m_max, v_max,
                                        g_med, b_med, m_med, v_med, out);
}